// Round 13
// baseline (530.966 us; speedup 1.0000x reference)
//
#include <hip/hip_runtime.h>

// DAG GNN recommender: N=20000 nodes, E=320000 edges, H=256, L=3, OUT=128.
// R1: (h[src]@W) == (h@W)[src] -> per-node GEMM + edge aggregation.
// R2: atomic scatter -> CSR gather fused with epilogue.
// R3: gather h first (bf16), one K-concat GEMM per layer.
// R4: BM=64 x BN=256 (A read once), dbuf LDS, raw s_barrier + counted vmcnt.
// R5: TILE-ORDERED operand layout (1KB contiguous frag-ordered loads).
// R6: COLUMN-SLICED gather (64-feat slices), LDS-staged full-tile writes.
// R7: XCD-PINNED slices (2 XCDs own each 2.5MB slice -> L2-resident).
// R8: 16B row gathers + int4 index loads.
// R9: LDS-atomic edge-balanced gather -> 20x REGRESSION. REVERTED.
// R10: launch fusion (bext x12 -> 1, scans merged, cur-zero folded).
// R11: LN mega-fusion in GEMM epilogue -> REGRESSED (occ 7%). REVERTED.
// R12: GEMM BM=32 (625 blocks, 2.4/CU) + B direct from L2; LDS 80KB -> 8KB.
// R13: WAVE-PER-NODE gather: lane = edge(8) x octet(8) -> 8 edges' rows
//      loaded in PARALLEL lanes per iteration; dependent chain 16 -> 2-4
//      iters (R12 gather was latency-bound: 37% VALU, 1.5TB/s eff).
//      shfl_xor tree combine; block = 16 waves = one tile-block.
// Precision: bf16 hi/lo split GEMM, 3 terms (Ah*Bh + Ah*Bl + Al*Bh).

#define H 256
#define LAYERS 3
#define OUTD 128
#define LN_EPS 1e-5f

typedef short s16x8 __attribute__((ext_vector_type(8)));
typedef unsigned short u16x4 __attribute__((ext_vector_type(4)));
typedef unsigned short u16x8 __attribute__((ext_vector_type(8)));
typedef float f32x4 __attribute__((ext_vector_type(4)));

__device__ __forceinline__ unsigned short f2bf(float f) {
  unsigned int u = __float_as_uint(f);
  u += 0x7FFFu + ((u >> 16) & 1u);     // round-to-nearest-even
  return (unsigned short)(u >> 16);
}
__device__ __forceinline__ float bf2f(unsigned short s) {
  return __uint_as_float(((unsigned int)s) << 16);
}
__device__ __forceinline__ float gelu_f(float x) {
  return 0.5f * x * (1.0f + erff(x * 0.70710678118654752440f));
}
__device__ __forceinline__ void gload16(const void* g, void* l) {
  __builtin_amdgcn_global_load_lds((const __attribute__((address_space(1))) void*)g,
                                   (__attribute__((address_space(3))) void*)l, 16, 0, 0);
}

// ---- Tile layout ----------------------------------------------------------
// Operands stored as 1KB tiles: tile t = (rb*NS + sec)*16 + c, c in 0..7 = hi
// k-chunk c (k = c*32..+31), c+8 = matching lo chunk. Within a tile:
// elem addr = (row&15)*8 + ((k>>3)&3)*128 + (k&7)  (= MFMA frag lane order).

// store hi/lo of 4 values at feature j=4l..4l+3 of `row` into tile section sec
__device__ __forceinline__ void store_split8(unsigned short* __restrict__ T, int NS, int sec,
                                             int row, int l, u16x4 hv, u16x4 lv) {
  size_t tb = ((size_t)((row >> 4) * NS + sec) << 4) + (l >> 3);
  int off = (((row & 15) + (((l >> 1) & 3) << 4)) << 3) + ((l & 1) << 2);
  *(u16x4*)(T + tb * 512 + off) = hv;
  *(u16x4*)(T + (tb + 8) * 512 + off) = lv;
}

// X [M][256] f32 -> tile-ordered hi/lo split (section 0 of NS), plus
// optional compact bf16-hi copy. One block per 16-row tile-block.
__global__ void split_tiles_kernel(const float* __restrict__ X,
                                   unsigned short* __restrict__ T, int NS,
                                   unsigned short* __restrict__ Hc, int M)
{
  const int rb = blockIdx.x;
  const int l = threadIdx.x & 63;
  const int cq = threadIdx.x >> 6;
  const int row = (rb << 4) + (l & 15);
  if (row >= M) return;
  const float* xr = X + (size_t)row * H;
#pragma unroll
  for (int p = 0; p < 2; ++p) {
    const int c = cq + (p << 2);
    const int j0 = (c << 5) + ((l >> 4) << 3);
    f32x4 v0 = *(const f32x4*)(xr + j0);
    f32x4 v1 = *(const f32x4*)(xr + j0 + 4);
    u16x8 hv, lv;
#pragma unroll
    for (int i = 0; i < 4; ++i) {
      unsigned short hb = f2bf(v0[i]); hv[i] = hb;     lv[i] = f2bf(v0[i] - bf2f(hb));
      unsigned short hc = f2bf(v1[i]); hv[4 + i] = hc; lv[4 + i] = f2bf(v1[i] - bf2f(hc));
    }
    size_t tb = ((size_t)(rb * NS) << 4);
    *(u16x8*)(T + (tb + c) * 512 + (l << 3)) = hv;
    *(u16x8*)(T + (tb + c + 8) * 512 + (l << 3)) = lv;
    if (Hc) *(u16x8*)(Hc + (size_t)row * H + j0) = hv;
  }
}

// ALL weights -> tile-ordered hi/lo in one launch. blockIdx = slot*256 + chunk.
__global__ void bext_all_kernel(const float* __restrict__ in_w,
                                const float* __restrict__ parent_w,
                                const float* __restrict__ child_w,
                                const float* __restrict__ self_w,
                                const float* __restrict__ head_w1,
                                const float* __restrict__ head_w2,
                                unsigned short* __restrict__ Bext)
{
  const int slot = blockIdx.x >> 8;
  const int chunk = blockIdx.x & 255;
  const int ncol = (slot == 11) ? OUTD : H;
  const int idx = chunk * 256 + threadIdx.x;
  if (idx >= H * ncol) return;
  const float* W =
    (slot == 0)  ? in_w :
    (slot <= 3)  ? parent_w + (size_t)(slot - 1) * H * H :
    (slot <= 6)  ? child_w  + (size_t)(slot - 4) * H * H :
    (slot <= 9)  ? self_w   + (size_t)(slot - 7) * H * H :
    (slot == 10) ? head_w1  : head_w2;
  unsigned short* Bt = Bext + (size_t)slot * H * 512;
  int k = idx / ncol;
  int n = idx - k * ncol;
  float w = W[idx];
  unsigned short hb = f2bf(w);
  unsigned short lb = f2bf(w - bf2f(hb));
  size_t base = (((size_t)(n >> 4) << 4) + (k >> 5)) * 512 +
                (((n & 15) + (((k >> 3) & 3) << 4)) << 3) + (k & 7);
  Bt[base] = hb;
  Bt[base + 8 * 512] = lb;
}

__global__ void zero2_kernel(int* __restrict__ a, int* __restrict__ b, int n) {
  int i = blockIdx.x * 256 + threadIdx.x;
  if (i < n) { a[i] = 0; b[i] = 0; }
}

__global__ void deg_kernel(const int* __restrict__ src, const int* __restrict__ dst,
                           int* __restrict__ di, int* __restrict__ dox, int E) {
  int e = blockIdx.x * 256 + threadIdx.x;
  if (e >= E) return;
  atomicAdd(&dox[src[e]], 1);
  atomicAdd(&di[dst[e]], 1);
}

// 1/deg (clamped) + zero the CSR fill cursors.
__global__ void rdeg_kernel(const int* __restrict__ di, const int* __restrict__ dox,
                            float* __restrict__ ri, float* __restrict__ ro,
                            int* __restrict__ cur_in, int* __restrict__ cur_out, int n) {
  int i = blockIdx.x * 256 + threadIdx.x;
  if (i >= n) return;
  int a = di[i];  if (a < 1) a = 1;
  int b = dox[i]; if (b < 1) b = 1;
  ri[i] = 1.0f / (float)a;
  ro[i] = 1.0f / (float)b;
  cur_in[i] = 0;
  cur_out[i] = 0;
}

// Exclusive prefix scans of both degree arrays -> rowptrs; 2 blocks of 1024.
__global__ __launch_bounds__(1024)
void scan2_kernel(const int* __restrict__ degi, const int* __restrict__ dego,
                  int* __restrict__ rp_in, int* __restrict__ rp_out, int n) {
  __shared__ int partial[1024];
  const int* deg = blockIdx.x ? dego : degi;
  int* rowptr = blockIdx.x ? rp_out : rp_in;
  const int t = threadIdx.x;
  const int chunk = (n + 1023) / 1024;
  int b = t * chunk;
  int e = b + chunk; if (e > n) e = n;
  int s = 0;
  for (int i = b; i < e; ++i) s += deg[i];
  partial[t] = s;
  __syncthreads();
  for (int off = 1; off < 1024; off <<= 1) {
    int v = (t >= off) ? partial[t - off] : 0;
    __syncthreads();
    partial[t] += v;
    __syncthreads();
  }
  int run = (t == 0) ? 0 : partial[t - 1];
  for (int i = b; i < e; ++i) { rowptr[i] = run; run += deg[i]; }
  if (t == 1023) rowptr[n] = run;
}

// CSR fill: ci_in grouped by dst holds src; ci_out grouped by src holds dst.
__global__ void fill_kernel(const int* __restrict__ src, const int* __restrict__ dst,
                            const int* __restrict__ rp_in, const int* __restrict__ rp_out,
                            int* __restrict__ cur_in, int* __restrict__ cur_out,
                            int* __restrict__ ci_in, int* __restrict__ ci_out, int E) {
  int e = blockIdx.x * 256 + threadIdx.x;
  if (e >= E) return;
  int s = src[e], d = dst[e];
  int p = atomicAdd(&cur_in[d], 1);
  ci_in[rp_in[d] + p] = s;
  int q = atomicAdd(&cur_out[s], 1);
  ci_out[rp_out[s] + q] = d;
}

// C[32 x N] = A_tiles @ B_tiles over nsec K-sections (+bias)(+gelu).
// BM=32, 4 waves each = 32 rows x 64 cols (NF=4) or x32 (NF=2).
// A: LDS-staged (1 gload16/wave/step), shared. B: DIRECT from L2.
template<int NF>
__global__ __launch_bounds__(256)
void gemm_kernel(const unsigned short* __restrict__ A, int NSa,
                 const unsigned short* __restrict__ B0,
                 const unsigned short* __restrict__ B1,
                 const unsigned short* __restrict__ B2,
                 const float* __restrict__ bias, float* __restrict__ C,
                 int M, int nrb, int nsec, int do_gelu)
{
  constexpr int N = NF * 64;
  __shared__ unsigned short ldsA[2][2048];   // [buf][t0hi|t1hi|t0lo|t1lo] 4KB x2

  const int tid = threadIdx.x;
  const int lane = tid & 63;
  const int wn = tid >> 6;
  const int m0 = blockIdx.x << 5;
  int rbw = (blockIdx.x << 1) + (wn & 1);
  if (rbw >= nrb) rbw = nrb - 1;             // tail clamp (stores guarded)
  const int hilo = wn >> 1;                  // which half this wave stages

  f32x4 acc[2][NF] = {};

  auto STAGE = [&](int buf, int step) {
    const int s = step >> 3;
    const int c = step & 7;
    const unsigned short* pa =
        A + (((size_t)(rbw * NSa + s) << 4) + c + (hilo << 3)) * 512 + (lane << 3);
    gload16(pa, &ldsA[buf][0] + (wn << 9));
  };

  auto COMPUTE = [&](int buf, int step) {
    const int s = step >> 3;
    const int c = step & 7;
    const unsigned short* Bs = (s == 0) ? B0 : ((s == 1) ? B1 : B2);
    s16x8 bh[NF], bl[NF];
#pragma unroll
    for (int j = 0; j < NF; ++j) {           // B direct: 1KB coalesced per load
      const int g = wn * NF + j;
      bh[j] = *(const s16x8*)(Bs + ((size_t)((g << 4) + c) << 9) + (lane << 3));
      bl[j] = *(const s16x8*)(Bs + ((size_t)((g << 4) + c + 8) << 9) + (lane << 3));
    }
    const unsigned short* base = &ldsA[buf][0];
    s16x8 ah[2], al[2];
#pragma unroll
    for (int f = 0; f < 2; ++f) {
      ah[f] = *(const s16x8*)(base + (f << 9) + (lane << 3));
      al[f] = *(const s16x8*)(base + 1024 + (f << 9) + (lane << 3));
    }
#pragma unroll
    for (int i = 0; i < 2; ++i)
#pragma unroll
      for (int j = 0; j < NF; ++j)
        acc[i][j] = __builtin_amdgcn_mfma_f32_16x16x32_bf16(ah[i], bh[j], acc[i][j], 0, 0, 0);
#pragma unroll
    for (int i = 0; i < 2; ++i)
#pragma unroll
      for (int j = 0; j < NF; ++j)
        acc[i][j] = __builtin_amdgcn_mfma_f32_16x16x32_bf16(ah[i], bl[j], acc[i][j], 0, 0, 0);
#pragma unroll
    for (int i = 0; i < 2; ++i)
#pragma unroll
      for (int j = 0; j < NF; ++j)
        acc[i][j] = __builtin_amdgcn_mfma_f32_16x16x32_bf16(al[i], bh[j], acc[i][j], 0, 0, 0);
  };

  const int nsteps = nsec << 3;
  STAGE(0, 0);
  int cur = 0;
  for (int t = 0; t < nsteps - 1; ++t) {
    STAGE(cur ^ 1, t + 1);
    asm volatile("s_waitcnt vmcnt(1)" ::: "memory");
    __builtin_amdgcn_s_barrier();
    COMPUTE(cur, t);
    asm volatile("s_waitcnt lgkmcnt(0)" ::: "memory");   // ds_reads done before overwrite
    __builtin_amdgcn_s_barrier();
    cur ^= 1;
  }
  asm volatile("s_waitcnt vmcnt(0)" ::: "memory");
  __builtin_amdgcn_s_barrier();
  COMPUTE(cur, nsteps - 1);

  const int r0 = (lane >> 4) << 2;   // C/D: row=(lane>>4)*4+reg, col=lane&15  [m89-verified]
  const int cn = lane & 15;
#pragma unroll
  for (int j = 0; j < NF; ++j) {
    const int col = wn * (NF << 4) + (j << 4) + cn;
    const float bb = bias ? bias[col] : 0.0f;
#pragma unroll
    for (int i = 0; i < 2; ++i) {
      const int rowb = m0 + (i << 4) + r0;
#pragma unroll
      for (int r = 0; r < 4; ++r) {
        const int rr = rowb + r;
        if (rr < M) {
          float v = acc[i][j][r] + bb;
          if (do_gelu) v = gelu_f(v);
          C[(size_t)rr * N + col] = v;
        }
      }
    }
  }
}

// R13 wave-per-node gather. Lane = e*8 + o (8 edges x 8 feat-octets):
// per iteration a wave loads 8 edges' 128B row-slices in parallel lanes;
// each lane accumulates octet o over edge subset {e, e+8, ...}; 3-step
// shfl_xor tree combines e-lanes. Block = 1024 thr = 16 waves = 1 tile-block.
// XCD-pinned: xcd = b&7, slice s = xcd>>1, rb = (b>>3)*2 + (xcd&1).
__global__ __launch_bounds__(1024)
void gather_kernel(
    const int* __restrict__ rp_in, const int* __restrict__ ci_in,
    const int* __restrict__ rp_out, const int* __restrict__ ci_out,
    const float* __restrict__ ri, const float* __restrict__ ro,
    const unsigned short* __restrict__ Hc, unsigned short* __restrict__ Aext,
    int M, int nrb)
{
  __shared__ unsigned short sh[2][2][2][512];     // [sec][hilo][cc][elems] 8KB
  const int b = blockIdx.x;
  const int xcd = b & 7;
  const int s = xcd >> 1;
  const int rb = ((b >> 3) << 1) + (xcd & 1);
  if (rb >= nrb) return;                          // whole block exits: sync-safe
  const int tid = threadIdx.x;
  const int w = tid >> 6;          // wave = node in tile-block (0..15)
  const int lane = tid & 63;
  const int e = lane >> 3;         // edge slot (0..7)
  const int o = lane & 7;          // feat octet (0..7)
  const int row = (rb << 4) + w;
  const int foff = (s << 6) + (o << 3);

  float hin[8] = {}, hout[8] = {};
  float wi = 0.f, wo = 0.f;
  if (row < M) {
    wi = ri[row];
    wo = ro[row];
#pragma unroll
    for (int dir = 0; dir < 2; ++dir) {
      const int* __restrict__ ci = dir ? ci_out : ci_in;
      float* acc = dir ? hout : hin;
      const int beg = dir ? rp_out[row] : rp_in[row];
      const int end = dir ? rp_out[row + 1] : rp_in[row + 1];
      int i0 = beg;
      // unroll x2: two independent 8-edge load groups in flight
      for (; i0 + 16 <= end; i0 += 16) {
        int ia = ci[i0 + e];
        int ib = ci[i0 + 8 + e];
        u16x8 a = *(const u16x8*)(Hc + ((size_t)ia << 8) + foff);
        u16x8 c = *(const u16x8*)(Hc + ((size_t)ib << 8) + foff);
#pragma unroll
        for (int z = 0; z < 8; ++z) acc[z] += bf2f(a[z]) + bf2f(c[z]);
      }
      for (; i0 < end; i0 += 8) {
        int i = i0 + e;
        if (i < end) {
          int ia = ci[i];
          u16x8 a = *(const u16x8*)(Hc + ((size_t)ia << 8) + foff);
#pragma unroll
          for (int z = 0; z < 8; ++z) acc[z] += bf2f(a[z]);
        }
      }
    }
    // combine the 8 e-lane partial sums (tree over lane bits 3..5)
#pragma unroll
    for (int m = 8; m < 64; m <<= 1)
#pragma unroll
      for (int z = 0; z < 8; ++z) {
        hin[z]  += __shfl_xor(hin[z], m, 64);
        hout[z] += __shfl_xor(hout[z], m, 64);
      }
  }

  // lanes 0..7 (e==0) stage the node's 64 slice-feats into tile layout
  if (lane < 8) {
    const int cc = o >> 2;
    const int pos = (w << 3) + ((o & 3) << 7);
    u16x8 hv, lv;
#pragma unroll
    for (int q = 0; q < 8; ++q) {
      float v = hin[q] * wi;
      unsigned short hb = f2bf(v);
      hv[q] = hb; lv[q] = f2bf(v - bf2f(hb));
    }
    *(u16x8*)(&sh[0][0][cc][pos]) = hv;
    *(u16x8*)(&sh[0][1][cc][pos]) = lv;
#pragma unroll
    for (int q = 0; q < 8; ++q) {
      float v = hout[q] * wo;
      unsigned short hb = f2bf(v);
      hv[q] = hb; lv[q] = f2bf(v - bf2f(hb));
    }
    *(u16x8*)(&sh[1][0][cc][pos]) = hv;
    *(u16x8*)(&sh[1][1][cc][pos]) = lv;
  }
  __syncthreads();

  // write 8 full tiles; 32 threads/tile, 32B/thread, 1KB contiguous per tile
  if (tid < 256) {
    const int tp = tid >> 5;
    const int q = tid & 31;
    const int sec = tp >> 2, hilo = (tp >> 1) & 1, c2 = tp & 1;
    const int cg = (s << 1) + c2 + (hilo << 3);   // global k-chunk 0..15
    size_t tile = ((size_t)(rb * 3 + 1 + sec) << 4) + cg;
    unsigned short* dstp = Aext + tile * 512;
    const unsigned short* srcp = &sh[sec][hilo][c2][0];
#pragma unroll
    for (int i = 0; i < 2; ++i)
      *(u16x8*)(dstp + (i << 8) + (q << 3)) = *(const u16x8*)(srcp + (i << 8) + (q << 3));
  }
}

// h' = LayerNorm(h + gelu(preact))*g + b; write h' fp32 + Hc + tile-split sec0.
__global__ void finalize_kernel(float* __restrict__ h, const float* __restrict__ P,
                                unsigned short* __restrict__ Aext,
                                unsigned short* __restrict__ Hc,
                                const float* __restrict__ g, const float* __restrict__ b, int M)
{
  int row = blockIdx.x * 4 + (threadIdx.x >> 6);
  if (row >= M) return;
  int l = threadIdx.x & 63;
  int j = l << 2;
  f32x4 hv = *(const f32x4*)(h + (size_t)row * H + j);
  f32x4 pv = *(const f32x4*)(P + (size_t)row * H + j);
  f32x4 t;
  float sum = 0.f, sq = 0.f;
#pragma unroll
  for (int i = 0; i < 4; ++i) {
    t[i] = hv[i] + gelu_f(pv[i]);
    sum += t[i];
    sq += t[i] * t[i];
  }
#pragma unroll
  for (int off = 1; off < 64; off <<= 1) {
    sum += __shfl_xor(sum, off, 64);
    sq  += __shfl_xor(sq, off, 64);
  }
  float mu = sum * (1.0f / H);
  float var = sq * (1.0f / H) - mu * mu;
  float rs = rsqrtf(var + LN_EPS);
  f32x4 outv;
  u16x4 hvv, lvv;
#pragma unroll
  for (int i = 0; i < 4; ++i) {
    outv[i] = (t[i] - mu) * rs * g[j + i] + b[j + i];
    unsigned short hb = f2bf(outv[i]);
    hvv[i] = hb;
    lvv[i] = f2bf(outv[i] - bf2f(hb));
  }
  *(f32x4*)(h + (size_t)row * H + j) = outv;
  *(u16x4*)(Hc + ((size_t)row << 8) + j) = hvv;
  store_split8(Aext, 3, 0, row, l, hvv, lvv);
}

extern "C" void kernel_launch(void* const* d_in, const int* in_sizes, int n_in,
                              void* d_out, int out_size, void* d_ws, size_t ws_size,
                              hipStream_t stream)
{
  const float* x        = (const float*)d_in[0];
  const int*   ei       = (const int*)d_in[1];
  const float* in_w     = (const float*)d_in[2];
  const float* in_b     = (const float*)d_in[3];
  const float* parent_w = (const float*)d_in[4];
  const float* child_w  = (const float*)d_in[5];
  const float* self_w   = (const float*)d_in[6];
  const float* self_b   = (const float*)d_in[7];
  const float* ln_g     = (const float*)d_in[8];
  const float* ln_b     = (const float*)d_in[9];
  const float* head_w1  = (const float*)d_in[10];
  const float* head_b1  = (const float*)d_in[11];
  const float* head_w2  = (const float*)d_in[12];
  const float* head_b2  = (const float*)d_in[13];

  const int M = in_sizes[0] / H;     // 20000
  const int E = in_sizes[1] / 2;     // 320000
  const int nrb = (M + 15) / 16;     // 1250
  const int* src = ei;
  const int* dst = ei + E;

  char* w = (char*)d_ws;
  auto alloc = [&](size_t bytes) { char* p = w; w += (bytes + 255) & ~(size_t)255; return p; };
  float*          h    = (float*)alloc((size_t)M * H * 4);
  float*          P    = (float*)alloc((size_t)M * H * 4);
  unsigned short* Ax   = (unsigned short*)alloc((size_t)nrb * 16 * 512 * 2);  // 1-section tiles
  unsigned short* Aext = (unsigned short*)alloc((size_t)nrb * 48 * 512 * 2);  // 3-section tiles
  unsigned short* Hc   = (unsigned short*)alloc((size_t)M * H * 2);
  unsigned short* Bext = (unsigned short*)alloc((size_t)12 * H * 512 * 2);
  int*            degi = (int*)alloc((size_t)M * 4);
  int*            dego = (int*)alloc((size_t)M * 4);
  float*          ri   = (float*)alloc((size_t)M * 4);
  float*          ro   = (float*)alloc((size_t)M * 4);
  int*            rp_in   = (int*)alloc((size_t)(M + 1) * 4);
  int*            rp_out  = (int*)alloc((size_t)(M + 1) * 4);
  int*            cur_in  = (int*)alloc((size_t)M * 4);
  int*            cur_out = (int*)alloc((size_t)M * 4);
  int*            ci_in   = (int*)alloc((size_t)E * 4);
  int*            ci_out  = (int*)alloc((size_t)E * 4);
  if ((size_t)(w - (char*)d_ws) > ws_size) return;  // insufficient scratch: fail loudly

  auto bslot = [&](int i) { return Bext + (size_t)i * H * 512; };

  // ALL weight hi/lo splits in one launch
  bext_all_kernel<<<12 * 256, 256, 0, stream>>>(in_w, parent_w, child_w, self_w,
                                                head_w1, head_w2, Bext);

  // Degrees + CSR build (layer-invariant)
  zero2_kernel<<<(M + 255) / 256, 256, 0, stream>>>(degi, dego, M);
  deg_kernel<<<(E + 255) / 256, 256, 0, stream>>>(src, dst, degi, dego, E);
  rdeg_kernel<<<(M + 255) / 256, 256, 0, stream>>>(degi, dego, ri, ro, cur_in, cur_out, M);
  scan2_kernel<<<2, 1024, 0, stream>>>(degi, dego, rp_in, rp_out, M);
  fill_kernel<<<(E + 255) / 256, 256, 0, stream>>>(src, dst, rp_in, rp_out,
                                                   cur_in, cur_out, ci_in, ci_out, E);

  const int mb32 = (M + 31) / 32;               // 625
  const int ggrid = (M + 3) / 4;
  const int xgrid = 8 * ((nrb + 1) / 2);        // XCD-pinned wave-per-node grid

  // h = x @ in_w + in_b; then split h into Aext sec0 tiles + Hc
  split_tiles_kernel<<<nrb, 256, 0, stream>>>(x, Ax, 1, nullptr, M);
  gemm_kernel<4><<<mb32, 256, 0, stream>>>(Ax, 1, bslot(0), nullptr, nullptr,
                                           in_b, h, M, nrb, 1, 0);
  split_tiles_kernel<<<nrb, 256, 0, stream>>>(h, Aext, 3, Hc, M);

  for (int l = 0; l < LAYERS; ++l) {
    gather_kernel<<<xgrid, 1024, 0, stream>>>(rp_in, ci_in, rp_out, ci_out,
                                              ri, ro, Hc, Aext, M, nrb);
    gemm_kernel<4><<<mb32, 256, 0, stream>>>(Aext, 3,
                                             bslot(7 + l), bslot(1 + l), bslot(4 + l),
                                             self_b + (size_t)l * H, P, M, nrb, 3, 0);
    finalize_kernel<<<ggrid, 256, 0, stream>>>(h, P, Aext, Hc,
                                               ln_g + (size_t)l * H, ln_b + (size_t)l * H, M);
  }

  // Head: P = gelu(h@w1+b1); split P; y = P@w2 + b2
  gemm_kernel<4><<<mb32, 256, 0, stream>>>(Aext, 3, bslot(10), nullptr, nullptr,
                                           head_b1, P, M, nrb, 1, 1);
  split_tiles_kernel<<<nrb, 256, 0, stream>>>(P, Ax, 1, nullptr, M);
  gemm_kernel<2><<<mb32, 256, 0, stream>>>(Ax, 1, bslot(11), nullptr, nullptr,
                                           head_b2, (float*)d_out, M, nrb, 1, 0);
}

// Round 14
// 441.516 us; speedup vs baseline: 1.2026x; 1.2026x over previous
//
#include <hip/hip_runtime.h>

// DAG GNN recommender: N=20000 nodes, E=320000 edges, H=256, L=3, OUT=128.
// R1-R8: see history. R9 (LDS-atomic gather) REVERTED. R11 (LN mega-fusion)
// REVERTED. R13 (wave-per-node gather) REVERTED — fixed 192-op shfl combine
// dwarfs deg=16 accumulate work.
// R12: GEMM BM=32 (625 blocks, 2.4/CU) + B direct from L2; LDS 80KB -> 8KB.
// R14: (a) gather blocks 256->128 thr (16 nodes): ~19.5 blocks/CU for finer
//      tail packing (R12 occ was 47% from max-deg-of-32 block skew);
//      (b) split fused into LIGHT epilogues only (in-proj: h+sec0+Hc;
//      head1: gelu+Ax tiles) — per-element, no cross-lane state (R11 lesson).
// Precision: bf16 hi/lo split GEMM, 3 terms (Ah*Bh + Ah*Bl + Al*Bh).

#define H 256
#define LAYERS 3
#define OUTD 128
#define LN_EPS 1e-5f

typedef short s16x8 __attribute__((ext_vector_type(8)));
typedef unsigned short u16x4 __attribute__((ext_vector_type(4)));
typedef unsigned short u16x8 __attribute__((ext_vector_type(8)));
typedef float f32x4 __attribute__((ext_vector_type(4)));
typedef int i32x4 __attribute__((ext_vector_type(4)));

__device__ __forceinline__ unsigned short f2bf(float f) {
  unsigned int u = __float_as_uint(f);
  u += 0x7FFFu + ((u >> 16) & 1u);     // round-to-nearest-even
  return (unsigned short)(u >> 16);
}
__device__ __forceinline__ float bf2f(unsigned short s) {
  return __uint_as_float(((unsigned int)s) << 16);
}
__device__ __forceinline__ float gelu_f(float x) {
  return 0.5f * x * (1.0f + erff(x * 0.70710678118654752440f));
}
__device__ __forceinline__ void gload16(const void* g, void* l) {
  __builtin_amdgcn_global_load_lds((const __attribute__((address_space(1))) void*)g,
                                   (__attribute__((address_space(3))) void*)l, 16, 0, 0);
}

// ---- Tile layout ----------------------------------------------------------
// Operands stored as 1KB tiles: tile t = (rb*NS + sec)*16 + c, c in 0..7 = hi
// k-chunk c (k = c*32..+31), c+8 = matching lo chunk. Within a tile:
// elem addr = (row&15)*8 + ((k>>3)&3)*128 + (k&7)  (= MFMA frag lane order).

// store hi/lo of 4 values at feature j=4l..4l+3 of `row` into tile section sec
__device__ __forceinline__ void store_split8(unsigned short* __restrict__ T, int NS, int sec,
                                             int row, int l, u16x4 hv, u16x4 lv) {
  size_t tb = ((size_t)((row >> 4) * NS + sec) << 4) + (l >> 3);
  int off = (((row & 15) + (((l >> 1) & 3) << 4)) << 3) + ((l & 1) << 2);
  *(u16x4*)(T + tb * 512 + off) = hv;
  *(u16x4*)(T + (tb + 8) * 512 + off) = lv;
}

// X [M][256] f32 -> tile-ordered hi/lo split (section 0 of NS), plus
// optional compact bf16-hi copy. One block per 16-row tile-block.
__global__ void split_tiles_kernel(const float* __restrict__ X,
                                   unsigned short* __restrict__ T, int NS,
                                   unsigned short* __restrict__ Hc, int M)
{
  const int rb = blockIdx.x;
  const int l = threadIdx.x & 63;
  const int cq = threadIdx.x >> 6;
  const int row = (rb << 4) + (l & 15);
  if (row >= M) return;
  const float* xr = X + (size_t)row * H;
#pragma unroll
  for (int p = 0; p < 2; ++p) {
    const int c = cq + (p << 2);
    const int j0 = (c << 5) + ((l >> 4) << 3);
    f32x4 v0 = *(const f32x4*)(xr + j0);
    f32x4 v1 = *(const f32x4*)(xr + j0 + 4);
    u16x8 hv, lv;
#pragma unroll
    for (int i = 0; i < 4; ++i) {
      unsigned short hb = f2bf(v0[i]); hv[i] = hb;     lv[i] = f2bf(v0[i] - bf2f(hb));
      unsigned short hc = f2bf(v1[i]); hv[4 + i] = hc; lv[4 + i] = f2bf(v1[i] - bf2f(hc));
    }
    size_t tb = ((size_t)(rb * NS) << 4);
    *(u16x8*)(T + (tb + c) * 512 + (l << 3)) = hv;
    *(u16x8*)(T + (tb + c + 8) * 512 + (l << 3)) = lv;
    if (Hc) *(u16x8*)(Hc + (size_t)row * H + j0) = hv;
  }
}

// ALL weights -> tile-ordered hi/lo in one launch. blockIdx = slot*256 + chunk.
__global__ void bext_all_kernel(const float* __restrict__ in_w,
                                const float* __restrict__ parent_w,
                                const float* __restrict__ child_w,
                                const float* __restrict__ self_w,
                                const float* __restrict__ head_w1,
                                const float* __restrict__ head_w2,
                                unsigned short* __restrict__ Bext)
{
  const int slot = blockIdx.x >> 8;
  const int chunk = blockIdx.x & 255;
  const int ncol = (slot == 11) ? OUTD : H;
  const int idx = chunk * 256 + threadIdx.x;
  if (idx >= H * ncol) return;
  const float* W =
    (slot == 0)  ? in_w :
    (slot <= 3)  ? parent_w + (size_t)(slot - 1) * H * H :
    (slot <= 6)  ? child_w  + (size_t)(slot - 4) * H * H :
    (slot <= 9)  ? self_w   + (size_t)(slot - 7) * H * H :
    (slot == 10) ? head_w1  : head_w2;
  unsigned short* Bt = Bext + (size_t)slot * H * 512;
  int k = idx / ncol;
  int n = idx - k * ncol;
  float w = W[idx];
  unsigned short hb = f2bf(w);
  unsigned short lb = f2bf(w - bf2f(hb));
  size_t base = (((size_t)(n >> 4) << 4) + (k >> 5)) * 512 +
                (((n & 15) + (((k >> 3) & 3) << 4)) << 3) + (k & 7);
  Bt[base] = hb;
  Bt[base + 8 * 512] = lb;
}

__global__ void zero2_kernel(int* __restrict__ a, int* __restrict__ b, int n) {
  int i = blockIdx.x * 256 + threadIdx.x;
  if (i < n) { a[i] = 0; b[i] = 0; }
}

__global__ void deg_kernel(const int* __restrict__ src, const int* __restrict__ dst,
                           int* __restrict__ di, int* __restrict__ dox, int E) {
  int e = blockIdx.x * 256 + threadIdx.x;
  if (e >= E) return;
  atomicAdd(&dox[src[e]], 1);
  atomicAdd(&di[dst[e]], 1);
}

// 1/deg (clamped) + zero the CSR fill cursors.
__global__ void rdeg_kernel(const int* __restrict__ di, const int* __restrict__ dox,
                            float* __restrict__ ri, float* __restrict__ ro,
                            int* __restrict__ cur_in, int* __restrict__ cur_out, int n) {
  int i = blockIdx.x * 256 + threadIdx.x;
  if (i >= n) return;
  int a = di[i];  if (a < 1) a = 1;
  int b = dox[i]; if (b < 1) b = 1;
  ri[i] = 1.0f / (float)a;
  ro[i] = 1.0f / (float)b;
  cur_in[i] = 0;
  cur_out[i] = 0;
}

// Exclusive prefix scans of both degree arrays -> rowptrs; 2 blocks of 1024.
__global__ __launch_bounds__(1024)
void scan2_kernel(const int* __restrict__ degi, const int* __restrict__ dego,
                  int* __restrict__ rp_in, int* __restrict__ rp_out, int n) {
  __shared__ int partial[1024];
  const int* deg = blockIdx.x ? dego : degi;
  int* rowptr = blockIdx.x ? rp_out : rp_in;
  const int t = threadIdx.x;
  const int chunk = (n + 1023) / 1024;
  int b = t * chunk;
  int e = b + chunk; if (e > n) e = n;
  int s = 0;
  for (int i = b; i < e; ++i) s += deg[i];
  partial[t] = s;
  __syncthreads();
  for (int off = 1; off < 1024; off <<= 1) {
    int v = (t >= off) ? partial[t - off] : 0;
    __syncthreads();
    partial[t] += v;
    __syncthreads();
  }
  int run = (t == 0) ? 0 : partial[t - 1];
  for (int i = b; i < e; ++i) { rowptr[i] = run; run += deg[i]; }
  if (t == 1023) rowptr[n] = run;
}

// CSR fill: ci_in grouped by dst holds src; ci_out grouped by src holds dst.
__global__ void fill_kernel(const int* __restrict__ src, const int* __restrict__ dst,
                            const int* __restrict__ rp_in, const int* __restrict__ rp_out,
                            int* __restrict__ cur_in, int* __restrict__ cur_out,
                            int* __restrict__ ci_in, int* __restrict__ ci_out, int E) {
  int e = blockIdx.x * 256 + threadIdx.x;
  if (e >= E) return;
  int s = src[e], d = dst[e];
  int p = atomicAdd(&cur_in[d], 1);
  ci_in[rp_in[d] + p] = s;
  int q = atomicAdd(&cur_out[s], 1);
  ci_out[rp_out[s] + q] = d;
}

// C[32 x N] = A_tiles @ B_tiles over nsec K-sections (+bias).
// BM=32, 4 waves each = 32 rows x 64 cols (NF=4) or x32 (NF=2).
// A: LDS-staged (1 gload16/wave/step), shared. B: DIRECT from L2.
// GELU: apply gelu. SPLIT: also write bf16 hi/lo tiles (Asp, NSp) and
// optional Hc (per-element epilogue only — no cross-lane state, R11 lesson).
template<int NF, int GELU, int SPLIT>
__global__ __launch_bounds__(256)
void gemm_kernel(const unsigned short* __restrict__ A, int NSa,
                 const unsigned short* __restrict__ B0,
                 const unsigned short* __restrict__ B1,
                 const unsigned short* __restrict__ B2,
                 const float* __restrict__ bias, float* __restrict__ C,
                 unsigned short* __restrict__ Asp, int NSp,
                 unsigned short* __restrict__ Hc,
                 int M, int nrb, int nsec)
{
  constexpr int N = NF * 64;
  __shared__ unsigned short ldsA[2][2048];   // [buf][t0hi|t1hi|t0lo|t1lo] 4KB x2

  const int tid = threadIdx.x;
  const int lane = tid & 63;
  const int wn = tid >> 6;
  const int m0 = blockIdx.x << 5;
  int rbw = (blockIdx.x << 1) + (wn & 1);
  if (rbw >= nrb) rbw = nrb - 1;             // tail clamp (stores guarded)
  const int hilo = wn >> 1;                  // which half this wave stages

  f32x4 acc[2][NF] = {};

  auto STAGE = [&](int buf, int step) {
    const int s = step >> 3;
    const int c = step & 7;
    const unsigned short* pa =
        A + (((size_t)(rbw * NSa + s) << 4) + c + (hilo << 3)) * 512 + (lane << 3);
    gload16(pa, &ldsA[buf][0] + (wn << 9));
  };

  auto COMPUTE = [&](int buf, int step) {
    const int s = step >> 3;
    const int c = step & 7;
    const unsigned short* Bs = (s == 0) ? B0 : ((s == 1) ? B1 : B2);
    s16x8 bh[NF], bl[NF];
#pragma unroll
    for (int j = 0; j < NF; ++j) {           // B direct: 1KB coalesced per load
      const int g = wn * NF + j;
      bh[j] = *(const s16x8*)(Bs + ((size_t)((g << 4) + c) << 9) + (lane << 3));
      bl[j] = *(const s16x8*)(Bs + ((size_t)((g << 4) + c + 8) << 9) + (lane << 3));
    }
    const unsigned short* base = &ldsA[buf][0];
    s16x8 ah[2], al[2];
#pragma unroll
    for (int f = 0; f < 2; ++f) {
      ah[f] = *(const s16x8*)(base + (f << 9) + (lane << 3));
      al[f] = *(const s16x8*)(base + 1024 + (f << 9) + (lane << 3));
    }
#pragma unroll
    for (int i = 0; i < 2; ++i)
#pragma unroll
      for (int j = 0; j < NF; ++j)
        acc[i][j] = __builtin_amdgcn_mfma_f32_16x16x32_bf16(ah[i], bh[j], acc[i][j], 0, 0, 0);
#pragma unroll
    for (int i = 0; i < 2; ++i)
#pragma unroll
      for (int j = 0; j < NF; ++j)
        acc[i][j] = __builtin_amdgcn_mfma_f32_16x16x32_bf16(ah[i], bl[j], acc[i][j], 0, 0, 0);
#pragma unroll
    for (int i = 0; i < 2; ++i)
#pragma unroll
      for (int j = 0; j < NF; ++j)
        acc[i][j] = __builtin_amdgcn_mfma_f32_16x16x32_bf16(al[i], bh[j], acc[i][j], 0, 0, 0);
  };

  const int nsteps = nsec << 3;
  STAGE(0, 0);
  int cur = 0;
  for (int t = 0; t < nsteps - 1; ++t) {
    STAGE(cur ^ 1, t + 1);
    asm volatile("s_waitcnt vmcnt(1)" ::: "memory");
    __builtin_amdgcn_s_barrier();
    COMPUTE(cur, t);
    asm volatile("s_waitcnt lgkmcnt(0)" ::: "memory");   // ds_reads done before overwrite
    __builtin_amdgcn_s_barrier();
    cur ^= 1;
  }
  asm volatile("s_waitcnt vmcnt(0)" ::: "memory");
  __builtin_amdgcn_s_barrier();
  COMPUTE(cur, nsteps - 1);

  const int r0 = (lane >> 4) << 2;   // C/D: row=(lane>>4)*4+reg, col=lane&15  [m89-verified]
  const int cn = lane & 15;
#pragma unroll
  for (int j = 0; j < NF; ++j) {
    const int col = wn * (NF << 4) + (j << 4) + cn;
    const float bb = bias ? bias[col] : 0.0f;
#pragma unroll
    for (int i = 0; i < 2; ++i) {
      const int rowb = m0 + (i << 4) + r0;
#pragma unroll
      for (int r = 0; r < 4; ++r) {
        const int rr = rowb + r;
        if (rr < M) {
          float v = acc[i][j][r] + bb;
          if (GELU) v = gelu_f(v);
          if (C) C[(size_t)rr * N + col] = v;
          if (SPLIT) {
            unsigned short hb = f2bf(v);
            size_t tb = (((size_t)(rr >> 4) * NSp) << 4) + (col >> 5);
            int off = ((rr & 15) << 3) + (((col >> 3) & 3) << 7) + (col & 7);
            Asp[tb * 512 + off] = hb;
            Asp[(tb + 8) * 512 + off] = f2bf(v - bf2f(hb));
            if (Hc) Hc[((size_t)rr << 8) + col] = hb;
          }
        }
      }
    }
  }
}

// 8-feat (16B) gather accumulate with int4-vectorized index loads (R8 form).
__device__ __forceinline__ void gacc8(const int* __restrict__ ci, int beg, int end,
                                      const unsigned short* __restrict__ Hc, int foff,
                                      float* __restrict__ acc) {
  int i = beg;
  for (; i < end && (i & 3); ++i) {            // peel to int4 alignment
    u16x8 a = *(const u16x8*)(Hc + ((size_t)ci[i] << 8) + foff);
#pragma unroll
    for (int z = 0; z < 8; ++z) acc[z] += bf2f(a[z]);
  }
  for (; i + 4 <= end; i += 4) {
    i32x4 id = *(const i32x4*)(ci + i);        // one load per 4 edges
    u16x8 a = *(const u16x8*)(Hc + ((size_t)id[0] << 8) + foff);
    u16x8 b = *(const u16x8*)(Hc + ((size_t)id[1] << 8) + foff);
    u16x8 c = *(const u16x8*)(Hc + ((size_t)id[2] << 8) + foff);
    u16x8 d = *(const u16x8*)(Hc + ((size_t)id[3] << 8) + foff);
#pragma unroll
    for (int z = 0; z < 8; ++z)
      acc[z] += (bf2f(a[z]) + bf2f(b[z])) + (bf2f(c[z]) + bf2f(d[z]));
  }
  for (; i < end; ++i) {
    u16x8 a = *(const u16x8*)(Hc + ((size_t)ci[i] << 8) + foff);
#pragma unroll
    for (int z = 0; z < 8; ++z) acc[z] += bf2f(a[z]);
  }
}

// R14 gather: block = 16 nodes x 8 threads = 128 thr (finer tail packing,
// ~19.5 blocks/CU). XCD-pinned: xcd = b&7, slice s = xcd>>1,
// rb = (b>>3)*2 + (xcd&1). Slice = 64 feats (2.5MB, L2-resident on 2 XCDs).
// LDS-staged full-tile writes (8 tiles x 16 thr, 1KB contiguous each).
__global__ __launch_bounds__(128)
void gather_kernel(
    const int* __restrict__ rp_in, const int* __restrict__ ci_in,
    const int* __restrict__ rp_out, const int* __restrict__ ci_out,
    const float* __restrict__ ri, const float* __restrict__ ro,
    const unsigned short* __restrict__ Hc, unsigned short* __restrict__ Aext,
    int M, int nrb)
{
  __shared__ unsigned short sh[2][2][2][512];     // [sec][hilo][cc][elems] 8KB
  const int b = blockIdx.x;
  const int xcd = b & 7;
  const int s = xcd >> 1;
  const int rb = ((b >> 3) << 1) + (xcd & 1);
  if (rb >= nrb) return;                          // whole block exits: sync-safe
  const int tid = threadIdx.x;
  const int g = tid >> 3;          // node in tile-block (0..15)
  const int t = tid & 7;           // feat octet within slice
  const int row = (rb << 4) + g;
  const int foff = (s << 6) + (t << 3);

  float hin[8] = {}, hout[8] = {};
  float wi = 0.f, wo = 0.f;
  if (row < M) {
    gacc8(ci_in,  rp_in[row],  rp_in[row + 1],  Hc, foff, hin);
    gacc8(ci_out, rp_out[row], rp_out[row + 1], Hc, foff, hout);
    wi = ri[row];
    wo = ro[row];
  }

  // split + stage in LDS at tile-layout position
  const int cc = t >> 2;
  const int pos = (g << 3) + ((t & 3) << 7);
  u16x8 hv, lv;
#pragma unroll
  for (int q = 0; q < 8; ++q) {
    float v = hin[q] * wi;
    unsigned short hb = f2bf(v);
    hv[q] = hb; lv[q] = f2bf(v - bf2f(hb));
  }
  *(u16x8*)(&sh[0][0][cc][pos]) = hv;
  *(u16x8*)(&sh[0][1][cc][pos]) = lv;
#pragma unroll
  for (int q = 0; q < 8; ++q) {
    float v = hout[q] * wo;
    unsigned short hb = f2bf(v);
    hv[q] = hb; lv[q] = f2bf(v - bf2f(hb));
  }
  *(u16x8*)(&sh[1][0][cc][pos]) = hv;
  *(u16x8*)(&sh[1][1][cc][pos]) = lv;
  __syncthreads();

  // write 8 full tiles; 16 threads/tile, 32 elems (64B)/thread, contiguous
  const int tp = tid >> 4;
  const int q = tid & 15;
  const int sec = tp >> 2, hilo = (tp >> 1) & 1, c2 = tp & 1;
  const int cg = (s << 1) + c2 + (hilo << 3);     // global k-chunk 0..15
  size_t tile = ((size_t)(rb * 3 + 1 + sec) << 4) + cg;
  unsigned short* dstp = Aext + tile * 512;
  const unsigned short* srcp = &sh[sec][hilo][c2][0];
#pragma unroll
  for (int i = 0; i < 4; ++i)
    *(u16x8*)(dstp + (i << 7) + (q << 3)) = *(const u16x8*)(srcp + (i << 7) + (q << 3));
}

// h' = LayerNorm(h + gelu(preact))*g + b; write h' fp32 + Hc + tile-split sec0.
__global__ void finalize_kernel(float* __restrict__ h, const float* __restrict__ P,
                                unsigned short* __restrict__ Aext,
                                unsigned short* __restrict__ Hc,
                                const float* __restrict__ g, const float* __restrict__ b, int M)
{
  int row = blockIdx.x * 4 + (threadIdx.x >> 6);
  if (row >= M) return;
  int l = threadIdx.x & 63;
  int j = l << 2;
  f32x4 hv = *(const f32x4*)(h + (size_t)row * H + j);
  f32x4 pv = *(const f32x4*)(P + (size_t)row * H + j);
  f32x4 t;
  float sum = 0.f, sq = 0.f;
#pragma unroll
  for (int i = 0; i < 4; ++i) {
    t[i] = hv[i] + gelu_f(pv[i]);
    sum += t[i];
    sq += t[i] * t[i];
  }
#pragma unroll
  for (int off = 1; off < 64; off <<= 1) {
    sum += __shfl_xor(sum, off, 64);
    sq  += __shfl_xor(sq, off, 64);
  }
  float mu = sum * (1.0f / H);
  float var = sq * (1.0f / H) - mu * mu;
  float rs = rsqrtf(var + LN_EPS);
  f32x4 outv;
  u16x4 hvv, lvv;
#pragma unroll
  for (int i = 0; i < 4; ++i) {
    outv[i] = (t[i] - mu) * rs * g[j + i] + b[j + i];
    unsigned short hb = f2bf(outv[i]);
    hvv[i] = hb;
    lvv[i] = f2bf(outv[i] - bf2f(hb));
  }
  *(f32x4*)(h + (size_t)row * H + j) = outv;
  *(u16x4*)(Hc + ((size_t)row << 8) + j) = hvv;
  store_split8(Aext, 3, 0, row, l, hvv, lvv);
}

extern "C" void kernel_launch(void* const* d_in, const int* in_sizes, int n_in,
                              void* d_out, int out_size, void* d_ws, size_t ws_size,
                              hipStream_t stream)
{
  const float* x        = (const float*)d_in[0];
  const int*   ei       = (const int*)d_in[1];
  const float* in_w     = (const float*)d_in[2];
  const float* in_b     = (const float*)d_in[3];
  const float* parent_w = (const float*)d_in[4];
  const float* child_w  = (const float*)d_in[5];
  const float* self_w   = (const float*)d_in[6];
  const float* self_b   = (const float*)d_in[7];
  const float* ln_g     = (const float*)d_in[8];
  const float* ln_b     = (const float*)d_in[9];
  const float* head_w1  = (const float*)d_in[10];
  const float* head_b1  = (const float*)d_in[11];
  const float* head_w2  = (const float*)d_in[12];
  const float* head_b2  = (const float*)d_in[13];

  const int M = in_sizes[0] / H;     // 20000
  const int E = in_sizes[1] / 2;     // 320000
  const int nrb = (M + 15) / 16;     // 1250
  const int* src = ei;
  const int* dst = ei + E;

  char* w = (char*)d_ws;
  auto alloc = [&](size_t bytes) { char* p = w; w += (bytes + 255) & ~(size_t)255; return p; };
  float*          h    = (float*)alloc((size_t)M * H * 4);
  float*          P    = (float*)alloc((size_t)M * H * 4);
  unsigned short* Ax   = (unsigned short*)alloc((size_t)nrb * 16 * 512 * 2);  // 1-section tiles
  unsigned short* Aext = (unsigned short*)alloc((size_t)nrb * 48 * 512 * 2);  // 3-section tiles
  unsigned short* Hc   = (unsigned short*)alloc((size_t)M * H * 2);
  unsigned short* Bext = (unsigned short*)alloc((size_t)12 * H * 512 * 2);
  int*            degi = (int*)alloc((size_t)M * 4);
  int*            dego = (int*)alloc((size_t)M * 4);
  float*          ri   = (float*)alloc((size_t)M * 4);
  float*          ro   = (float*)alloc((size_t)M * 4);
  int*            rp_in   = (int*)alloc((size_t)(M + 1) * 4);
  int*            rp_out  = (int*)alloc((size_t)(M + 1) * 4);
  int*            cur_in  = (int*)alloc((size_t)M * 4);
  int*            cur_out = (int*)alloc((size_t)M * 4);
  int*            ci_in   = (int*)alloc((size_t)E * 4);
  int*            ci_out  = (int*)alloc((size_t)E * 4);
  if ((size_t)(w - (char*)d_ws) > ws_size) return;  // insufficient scratch: fail loudly

  auto bslot = [&](int i) { return Bext + (size_t)i * H * 512; };

  // ALL weight hi/lo splits in one launch
  bext_all_kernel<<<12 * 256, 256, 0, stream>>>(in_w, parent_w, child_w, self_w,
                                                head_w1, head_w2, Bext);

  // Degrees + CSR build (layer-invariant)
  zero2_kernel<<<(M + 255) / 256, 256, 0, stream>>>(degi, dego, M);
  deg_kernel<<<(E + 255) / 256, 256, 0, stream>>>(src, dst, degi, dego, E);
  rdeg_kernel<<<(M + 255) / 256, 256, 0, stream>>>(degi, dego, ri, ro, cur_in, cur_out, M);
  scan2_kernel<<<2, 1024, 0, stream>>>(degi, dego, rp_in, rp_out, M);
  fill_kernel<<<(E + 255) / 256, 256, 0, stream>>>(src, dst, rp_in, rp_out,
                                                   cur_in, cur_out, ci_in, ci_out, E);

  const int mb32 = (M + 31) / 32;               // 625
  const int ggrid = (M + 3) / 4;
  const int xgrid = 8 * ((nrb + 1) / 2);        // XCD-pinned gather grid (5000)

  // h = x @ in_w + in_b; epilogue writes h + Aext sec0 tiles + Hc (fused split)
  split_tiles_kernel<<<nrb, 256, 0, stream>>>(x, Ax, 1, nullptr, M);
  gemm_kernel<4, 0, 1><<<mb32, 256, 0, stream>>>(Ax, 1, bslot(0), nullptr, nullptr,
                                                 in_b, h, Aext, 3, Hc, M, nrb, 1);

  for (int l = 0; l < LAYERS; ++l) {
    gather_kernel<<<xgrid, 128, 0, stream>>>(rp_in, ci_in, rp_out, ci_out,
                                             ri, ro, Hc, Aext, M, nrb);
    gemm_kernel<4, 0, 0><<<mb32, 256, 0, stream>>>(Aext, 3,
                                                   bslot(7 + l), bslot(1 + l), bslot(4 + l),
                                                   self_b + (size_t)l * H, P,
                                                   nullptr, 0, nullptr, M, nrb, 3);
    finalize_kernel<<<ggrid, 256, 0, stream>>>(h, P, Aext, Hc,
                                               ln_g + (size_t)l * H, ln_b + (size_t)l * H, M);
  }

  // Head: Ax = split(gelu(h@w1+b1)) fused epilogue; y = Ax@w2 + b2
  gemm_kernel<4, 1, 1><<<mb32, 256, 0, stream>>>(Aext, 3, bslot(10), nullptr, nullptr,
                                                 head_b1, nullptr, Ax, 1, nullptr, M, nrb, 1);
  gemm_kernel<2, 0, 0><<<mb32, 256, 0, stream>>>(Ax, 1, bslot(11), nullptr, nullptr,
                                                 head_b2, (float*)d_out, nullptr, 0, nullptr,
                                                 M, nrb, 1);
}